// Round 12
// baseline (248.860 us; speedup 1.0000x reference)
//
#include <hip/hip_runtime.h>
#include <hip/hip_bf16.h>

#define NROWS   32768          // 32*16*64 rows of dim 64
#define NCODE   8192
#define NSPL    8              // code-dimension splits
#define CSPL    (NCODE / NSPL) // 1024 codes per block
#define CHUNKS  (CSPL / 32)    // 32 LDS chunks of 32 codes
#define BP      80             // B LDS pitch in shorts (R9: zero conflicts)

// d_out element offsets (FLOAT32 elements):
// quantize(2097152), ind(32768), loss(1), cluster(8192), eavg(524288), embed(524288)
#define OUT_Q        0
#define OUT_IND      2097152
#define OUT_LOSS     2129920
#define OUT_CLUSTER  2129921
#define OUT_EAVG     2138113
#define OUT_EMBED    2662401

// workspace byte offsets — total 4,522,048 bytes
#define WS_LOSS     0            // f32 [1]
#define WS_TOTAL    4            // f32 [1]
#define WS_SE       64           // f32 [8192]  ||e_j||^2
#define WS_COUNTS   32832        // f32 [8192]
#define WS_ESUM     65600        // f32 [8192][64] ([code][k])
#define WS_PK       2162752      // u64 [32768] packed (dist|idx)
#define WS_BH       2424896      // bf16 bits [8192][64] = -2 * high split
#define WS_BM       3473472      // bf16 bits [8192][64] = -2 * mid split
// end: 4,522,048

typedef short v8s __attribute__((ext_vector_type(8)));
typedef float v4f __attribute__((ext_vector_type(4)));
#define MFMA16 __builtin_amdgcn_mfma_f32_16x16x32_bf16

__device__ __forceinline__ int pos_off(int c, int R, int k) {
    // pos_emb[(R>>2)*16 + (k>>2)][c*16 + (R&3)*4 + (k&3)], row stride 256
    return (((R >> 2) * 16 + (k >> 2)) << 8) + (c << 4) + ((R & 3) << 2) + (k & 3);
}

__device__ __forceinline__ unsigned short f2bfbits(float v) {
    __hip_bfloat16 h = __float2bfloat16(v);           // RNE
    union { __hip_bfloat16 h; unsigned short u; } c; c.h = h; return c.u;
}
__device__ __forceinline__ float bfbits2f(unsigned short u) {
    union { unsigned short u; __hip_bfloat16 h; } c; c.u = u; return __bfloat162float(c.h);
}

// ---------------- K0: B' = -2*splits, ||e||^2, and all ws init ------------
// 128 blocks x 256. se chain bit-identical to R5..R11. Also zeroes
// esum/counts/loss/total and 0xFF-inits pk (replaces memset nodes).
__global__ __launch_bounds__(256) void k_prep_embed(
    const float* __restrict__ embed, float* __restrict__ se,
    unsigned short* __restrict__ Bh, unsigned short* __restrict__ Bm,
    float* __restrict__ esum, float* __restrict__ counts,
    float* __restrict__ loss_ws, float* __restrict__ total_ws,
    unsigned long long* __restrict__ pk)
{
    __shared__ float tile[64][65];
    const int tid = threadIdx.x;
    const int t = blockIdx.x * 256 + tid;           // 0..32767
    const int j0 = blockIdx.x * 64;                 // 64 codes per block
    const int a = tid >> 6, b = tid & 63;

    // ws init (graph-node elimination)
    {
        float4 z = {0.f, 0.f, 0.f, 0.f};
        float4* e4 = (float4*)(esum + (size_t)t * 16);
        e4[0] = z; e4[1] = z; e4[2] = z; e4[3] = z;
        pk[t] = 0xFFFFFFFFFFFFFFFFull;
        if (t < NCODE) counts[t] = 0.f;
        if (t == 0) { *loss_ws = 0.f; *total_ws = 0.f; }
    }

#pragma unroll 4
    for (int p = 0; p < 16; ++p) {                  // coalesced embed load
        const int kk = p * 4 + a;
        tile[kk][b] = embed[(size_t)kk * NCODE + j0 + b];
    }
    __syncthreads();
#pragma unroll
    for (int i = 0; i < 16; ++i) {                  // -2-scaled splits (exact)
        const int k = a * 16 + i;
        float v = tile[k][b];
        float h = bfbits2f(f2bfbits(v));
        float r1 = v - h;
        float m = bfbits2f(f2bfbits(r1));
        Bh[(size_t)(j0 + b) * 64 + k] = f2bfbits(-2.f * h);   // exact scale
        Bm[(size_t)(j0 + b) * 64 + k] = f2bfbits(-2.f * m);
    }
    if (tid < 64) {                                 // exact sequential chain
        float s = 0.f;
#pragma unroll
        for (int k = 0; k < 64; ++k) { float v = tile[k][tid]; s = fmaf(v, v, s); }
        se[j0 + tid] = s;
    }
}

// ---------------- K1: MFMA GEMM-argmin — 4 m-tiles/wave (64 rows) ---------
// Grid 1024: rb = blk>>3 (256 rows), split = blk&7 (1024 codes). 4 waves of
// 64 rows each; each ds_read_b128 now feeds 8 MFMAs (was 4 in R11).
// All math chains bit-identical to R11 (folded -2*B, acc init = sx+se).
__global__ __launch_bounds__(256) void k_argmin_mfma(
    const float* __restrict__ x, const float* __restrict__ pos,
    const unsigned short* __restrict__ Bh, const unsigned short* __restrict__ Bm,
    const float* __restrict__ se, unsigned long long* __restrict__ pk)
{
    __shared__ __align__(16) short lB[2 * 2 * 32 * BP];   // dbuf x {h,m} x 32 codes
    const int tid = threadIdx.x;
    const int row0  = (blockIdx.x >> 3) * 256;
    const int split = blockIdx.x & 7;
    const int w = tid >> 6, lane = tid & 63;
    const int quad = lane >> 4, l15 = lane & 15;
    const int jbeg = split * CSPL;

    // ---- A-frags direct from global (identical split math to R7..R11) ----
    v8s af[4][2][2];
    float sqf[4];
#pragma unroll
    for (int mt = 0; mt < 4; ++mt) {
        const int n = row0 + w * 64 + mt * 16 + l15;
        const int c = (n >> 6) & 15, R = n & 63;
        const float* xrow = x + (size_t)n * 64;
        const float* prow = pos + ((R >> 2) * 16) * 256 + c * 16 + (R & 3) * 4;
        float sq = 0.f;
#pragma unroll
        for (int kh = 0; kh < 2; ++kh) {
            const int kb = kh * 32 + quad * 8;         // frag k-base
            const float4 x0 = *(const float4*)(xrow + kb);
            const float4 x1 = *(const float4*)(xrow + kb + 4);
            const float4 p0 = *(const float4*)(prow + (kb >> 2) * 256);
            const float4 p1 = *(const float4*)(prow + (kb >> 2) * 256 + 256);
            float vv[8] = {x0.x + p0.x, x0.y + p0.y, x0.z + p0.z, x0.w + p0.w,
                           x1.x + p1.x, x1.y + p1.y, x1.z + p1.z, x1.w + p1.w};
            v8s hf, mf;
#pragma unroll
            for (int i = 0; i < 8; ++i) {
                unsigned short uh = f2bfbits(vv[i]);
                float r1 = vv[i] - bfbits2f(uh);
                unsigned short um = f2bfbits(r1);
                hf[i] = (short)uh; mf[i] = (short)um;
                sq = fmaf(vv[i], vv[i], sq);
            }
            af[mt][0][kh] = hf; af[mt][1][kh] = mf;
        }
        sq += __shfl_xor(sq, 16, 64);                  // sum the 4 quads' k-parts
        sq += __shfl_xor(sq, 32, 64);                  // (row-const shift: argmin-inv)
        sqf[mt] = sq;
    }
    float sxr[4][4];
#pragma unroll
    for (int mt = 0; mt < 4; ++mt)
#pragma unroll
        for (int r = 0; r < 4; ++r)
            sxr[mt][r] = __shfl(sqf[mt], quad * 4 + r, 64);  // C-row = quad*4+reg

    // ---- stream B: 32-code chunks, LDS dbuf, register prefetch ----------
    const int ct = tid >> 3, ks = tid & 7;             // staging: code, 16B slot
    const int dst = ct * BP + ks * 8;
    float best[4][4]; int bidx[4][4];
#pragma unroll
    for (int mt = 0; mt < 4; ++mt)
#pragma unroll
        for (int r = 0; r < 4; ++r) { best[mt][r] = 3.402823466e38f; bidx[mt][r] = 0; }

    {   // prologue: chunk 0 -> buf 0
        const size_t g = (size_t)(jbeg + ct) * 64 + ks * 8;
        int4 q0 = *(const int4*)(Bh + g);
        int4 q1 = *(const int4*)(Bm + g);
        *(int4*)&lB[dst] = q0;
        *(int4*)&lB[32 * BP + dst] = q1;
    }
    float cse0 = se[jbeg + l15], cse1 = se[jbeg + 16 + l15];
    __syncthreads();

    int buf = 0;
    for (int c = 0; c < CHUNKS; ++c) {
        int4 q0, q1; float nse0 = 0.f, nse1 = 0.f;
        if (c < CHUNKS - 1) {                          // prefetch next chunk
            const int n0n = jbeg + (c + 1) * 32;
            const size_t g = (size_t)(n0n + ct) * 64 + ks * 8;
            q0 = *(const int4*)(Bh + g);
            q1 = *(const int4*)(Bm + g);
            nse0 = se[n0n + l15]; nse1 = se[n0n + 16 + l15];
        }
        const short* bb = &lB[buf * (2 * 32 * BP)];
#pragma unroll
        for (int t16 = 0; t16 < 2; ++t16) {
            const int boff = (t16 * 16 + l15) * BP + quad * 8;
            const v8s bh0 = *(const v8s*)&bb[boff];
            const v8s bh1 = *(const v8s*)&bb[boff + 32];
            const v8s bm0 = *(const v8s*)&bb[32 * BP + boff];
            const v8s bm1 = *(const v8s*)&bb[32 * BP + boff + 32];
            const float sev = t16 ? cse1 : cse0;
            const int j = jbeg + c * 32 + t16 * 16 + l15;
#pragma unroll
            for (int mt = 0; mt < 4; ++mt) {
                // acc init = sx + se; B carries -2 => d = acc directly
                v4f a = {sxr[mt][0] + sev, sxr[mt][1] + sev,
                         sxr[mt][2] + sev, sxr[mt][3] + sev};
                a = MFMA16(af[mt][1][0], bm0, a, 0, 0, 0);
                a = MFMA16(af[mt][1][1], bm1, a, 0, 0, 0);
                a = MFMA16(af[mt][1][0], bh0, a, 0, 0, 0);
                a = MFMA16(af[mt][1][1], bh1, a, 0, 0, 0);
                a = MFMA16(af[mt][0][0], bm0, a, 0, 0, 0);
                a = MFMA16(af[mt][0][1], bm1, a, 0, 0, 0);
                a = MFMA16(af[mt][0][0], bh0, a, 0, 0, 0);
                a = MFMA16(af[mt][0][1], bh1, a, 0, 0, 0);
#pragma unroll
                for (int r = 0; r < 4; ++r) {
                    if (a[r] < best[mt][r]) { best[mt][r] = a[r]; bidx[mt][r] = j; }
                }
            }
        }
        if (c < CHUNKS - 1) {                          // store prefetch, swap
            const int nb = buf ^ 1;
            *(int4*)&lB[nb * (2 * 32 * BP) + dst] = q0;
            *(int4*)&lB[nb * (2 * 32 * BP) + 32 * BP + dst] = q1;
            cse0 = nse0; cse1 = nse1;
            __syncthreads();
            buf = nb;
        }
    }

    // lane-reduce over 16 lanes per row, then packed global atomicMin.
    // key = monotone(dist)<<32 | idx == (min dist, lower idx) tie-break.
#pragma unroll
    for (int mt = 0; mt < 4; ++mt)
#pragma unroll
    for (int r = 0; r < 4; ++r) {
        float bv = best[mt][r]; int bi = bidx[mt][r];
#pragma unroll
        for (int m = 8; m >= 1; m >>= 1) {
            float ov = __shfl_xor(bv, m, 64);
            int   oi = __shfl_xor(bi, m, 64);
            if (ov < bv || (ov == bv && oi < bi)) { bv = ov; bi = oi; }
        }
        if (l15 == 0) {
            const int row = row0 + w * 64 + mt * 16 + quad * 4 + r;
            unsigned int kb = __float_as_uint(bv);
            kb = kb ^ (((int)kb >> 31) | 0x80000000u);   // order-preserving uint
            unsigned long long key =
                ((unsigned long long)kb << 32) | (unsigned int)bi;
            atomicMin(&pk[row], key);
        }
    }
}

// ---------------- K2: quantize gather + loss + EMA scatter (float4) ------
// 2048 blocks x 256: 16 rows/block, 16 threads x float4 per row.
__global__ __launch_bounds__(256) void k_quant(
    const float* __restrict__ x, const float* __restrict__ pos,
    const unsigned short* __restrict__ Bh, const unsigned short* __restrict__ Bm,
    const unsigned long long* __restrict__ pk,
    float* __restrict__ embed_sum, float* __restrict__ counts,
    float* __restrict__ loss_ws, float* __restrict__ out_q,
    float* __restrict__ out_ind)
{
    const int tid = threadIdx.x;
    const int rr = tid >> 4, sl = tid & 15;      // row-in-block, 4-elem slot
    const int n = blockIdx.x * 16 + rr;
    const int k0 = sl * 4;
    int idx = (int)(unsigned int)(pk[n] & 0xFFFFFFFFull);   // same addr x16: bcast
    idx = idx < 0 ? 0 : (idx > NCODE - 1 ? NCODE - 1 : idx);
    if (sl == 0) out_ind[n] = (float)idx;

    const size_t eo = (size_t)idx * 64 + k0;
    const ushort4 uh = *(const ushort4*)(Bh + eo);
    const ushort4 um = *(const ushort4*)(Bm + eo);
    // e = -0.5*(-2h + -2m): exact power-of-2 scale => identical to h+m
    float qv[4] = {-0.5f * (bfbits2f(uh.x) + bfbits2f(um.x)),
                   -0.5f * (bfbits2f(uh.y) + bfbits2f(um.y)),
                   -0.5f * (bfbits2f(uh.z) + bfbits2f(um.z)),
                   -0.5f * (bfbits2f(uh.w) + bfbits2f(um.w))};
    const float4 xv = *(const float4*)(x + (size_t)n * 64 + k0);
    *(float4*)(out_q + (size_t)n * 64 + k0) = make_float4(qv[0], qv[1], qv[2], qv[3]);

    const int c = (n >> 6) & 15, R = n & 63;
    const float4 pv = *(const float4*)(pos + (((R >> 2) * 16 + sl) << 8)
                                           + (c << 4) + ((R & 3) << 2));
    atomicAdd(&embed_sum[eo + 0], xv.x + pv.x);
    atomicAdd(&embed_sum[eo + 1], xv.y + pv.y);
    atomicAdd(&embed_sum[eo + 2], xv.z + pv.z);
    atomicAdd(&embed_sum[eo + 3], xv.w + pv.w);
    if (sl == 0) atomicAdd(&counts[idx], 1.0f);

    float sq = (qv[0] - xv.x) * (qv[0] - xv.x) + (qv[1] - xv.y) * (qv[1] - xv.y)
             + (qv[2] - xv.z) * (qv[2] - xv.z) + (qv[3] - xv.w) * (qv[3] - xv.w);
#pragma unroll
    for (int m = 32; m >= 1; m >>= 1) sq += __shfl_xor(sq, m, 64);
    __shared__ float ls[4];
    if ((tid & 63) == 0) ls[tid >> 6] = sq;
    __syncthreads();
    if (tid == 0) atomicAdd(loss_ws, ls[0] + ls[1] + ls[2] + ls[3]);
}

// ---------------- K3: cluster/total/eavg/embed/loss (merged final) --------
__global__ __launch_bounds__(256) void k_final(
    const float* __restrict__ cluster, const float* __restrict__ counts,
    const float* __restrict__ embed_avg, const float* __restrict__ embed_sum,
    const float* __restrict__ loss_ws,
    float* __restrict__ out_loss, float* __restrict__ out_cluster,
    float* __restrict__ out_eavg, float* __restrict__ out_embed)
{
    __shared__ float tile[64][65];
    __shared__ float smv[64];
    __shared__ float ls[4];
    __shared__ float tot_s;
    const int tid = threadIdx.x;
    const int j0 = blockIdx.x * 64;
    const int a = tid >> 6, b = tid & 63;

    // total = sum(new_cluster), identical order every block
    float s = 0.f;
#pragma unroll 4
    for (int p = 0; p < 32; ++p) {
        const int j = p * 256 + tid;
        s += 0.8f * cluster[j] + 0.2f * counts[j];
    }
#pragma unroll
    for (int m = 32; m >= 1; m >>= 1) s += __shfl_xor(s, m, 64);
    if ((tid & 63) == 0) ls[tid >> 6] = s;

#pragma unroll 4
    for (int p = 0; p < 16; ++p) {               // load esum tile coalesced
        const int jj = p * 4 + a;
        tile[jj][b] = embed_sum[(size_t)(j0 + jj) * 64 + b];
    }
    __syncthreads();
    if (tid == 0) tot_s = ls[0] + ls[1] + ls[2] + ls[3];
    __syncthreads();
    if (tid < 64) {
        const float total = tot_s;
        float nc = 0.8f * cluster[j0 + tid] + 0.2f * counts[j0 + tid];
        out_cluster[j0 + tid] = nc;
        smv[tid] = (nc + 1e-5f) / (total + 0.08192f) * total;
    }
    __syncthreads();

#pragma unroll 4
    for (int p = 0; p < 16; ++p) {               // write transposed, coalesced
        const int kk = p * 4 + a;
        const size_t e = (size_t)kk * NCODE + j0 + b;
        float ea = 0.8f * embed_avg[e] + 0.2f * tile[b][kk];
        out_eavg[e]  = ea;
        out_embed[e] = ea / smv[b];
    }
    if (blockIdx.x == 0 && tid == 0)
        *out_loss = *loss_ws * (1.0f / 2097152.0f);
}

extern "C" void kernel_launch(void* const* d_in, const int* in_sizes, int n_in,
                              void* d_out, int out_size, void* d_ws, size_t ws_size,
                              hipStream_t stream) {
    (void)in_sizes; (void)n_in; (void)out_size; (void)ws_size;
    const float* x        = (const float*)d_in[0];   // (32,16,64,64)
    const float* embed    = (const float*)d_in[1];   // (64,8192)
    const float* pos      = (const float*)d_in[2];   // (2048,256)
    const float* cluster  = (const float*)d_in[3];   // (8192,)
    const float* eavg     = (const float*)d_in[4];   // (64,8192)
    float* out = (float*)d_out;                      // fp32 outputs, concatenated

    char* ws = (char*)d_ws;
    float* w_loss   = (float*)(ws + WS_LOSS);
    float* w_total  = (float*)(ws + WS_TOTAL);
    float* w_se     = (float*)(ws + WS_SE);
    float* w_counts = (float*)(ws + WS_COUNTS);
    float* w_esum   = (float*)(ws + WS_ESUM);
    unsigned long long* w_pk = (unsigned long long*)(ws + WS_PK);
    unsigned short* w_bh = (unsigned short*)(ws + WS_BH);
    unsigned short* w_bm = (unsigned short*)(ws + WS_BM);

    // 4 graph nodes; prep performs all workspace init (no memsets)
    k_prep_embed<<<NROWS / 256, 256, 0, stream>>>(embed, w_se, w_bh, w_bm,
                                                  w_esum, w_counts, w_loss,
                                                  w_total, w_pk);
    k_argmin_mfma<<<(NROWS / 256) * NSPL, 256, 0, stream>>>(
        x, pos, w_bh, w_bm, w_se, w_pk);
    k_quant<<<NROWS / 16, 256, 0, stream>>>(x, pos, w_bh, w_bm, w_pk,
                                            w_esum, w_counts, w_loss,
                                            out + OUT_Q, out + OUT_IND);
    k_final<<<NCODE / 64, 256, 0, stream>>>(cluster, w_counts, eavg, w_esum,
                                            w_loss, out + OUT_LOSS,
                                            out + OUT_CLUSTER,
                                            out + OUT_EAVG, out + OUT_EMBED);
}

// Round 13
// 245.046 us; speedup vs baseline: 1.0156x; 1.0156x over previous
//
#include <hip/hip_runtime.h>
#include <hip/hip_bf16.h>

#define NROWS   32768          // 32*16*64 rows of dim 64
#define NCODE   8192
#define NSPL    8              // code-dimension splits
#define CSPL    (NCODE / NSPL) // 1024 codes per block
#define CHUNKS  (CSPL / 32)    // 32 LDS chunks of 32 codes

// d_out element offsets (FLOAT32 elements):
// quantize(2097152), ind(32768), loss(1), cluster(8192), eavg(524288), embed(524288)
#define OUT_Q        0
#define OUT_IND      2097152
#define OUT_LOSS     2129920
#define OUT_CLUSTER  2129921
#define OUT_EAVG     2138113
#define OUT_EMBED    2662401

// workspace byte offsets — total 4,522,048 bytes
#define WS_LOSS     0            // f32 [1]
#define WS_TOTAL    4            // f32 [1]
#define WS_SE       64           // f32 [8192]  ||e_j||^2
#define WS_COUNTS   32832        // f32 [8192]
#define WS_ESUM     65600        // f32 [8192][64] ([code][k])
#define WS_PK       2162752      // u64 [32768] packed (dist|idx)
#define WS_BH       2424896      // bf16 bits [8192][64] = -2 * high split
#define WS_BM       3473472      // bf16 bits [8192][64] = -2 * mid split
// end: 4,522,048

typedef short v8s __attribute__((ext_vector_type(8)));
typedef float v4f __attribute__((ext_vector_type(4)));
#define MFMA16 __builtin_amdgcn_mfma_f32_16x16x32_bf16

__device__ __forceinline__ int pos_off(int c, int R, int k) {
    // pos_emb[(R>>2)*16 + (k>>2)][c*16 + (R&3)*4 + (k&3)], row stride 256
    return (((R >> 2) * 16 + (k >> 2)) << 8) + (c << 4) + ((R & 3) << 2) + (k & 3);
}

__device__ __forceinline__ unsigned short f2bfbits(float v) {
    __hip_bfloat16 h = __float2bfloat16(v);           // RNE
    union { __hip_bfloat16 h; unsigned short u; } c; c.h = h; return c.u;
}
__device__ __forceinline__ float bfbits2f(unsigned short u) {
    union { unsigned short u; __hip_bfloat16 h; } c; c.u = u; return __bfloat162float(c.h);
}

// direct global->LDS 16B DMA (gfx950): dest = wave-uniform base + lane*16
__device__ __forceinline__ void gld_lds16(const unsigned short* g, short* lds_base) {
    __builtin_amdgcn_global_load_lds(
        (const __attribute__((address_space(1))) unsigned int*)g,
        (__attribute__((address_space(3))) unsigned int*)lds_base, 16, 0, 0);
}

// ---------------- K0: B' = -2*splits, ||e||^2, and all ws init ------------
// 128 blocks x 256. se chain bit-identical to R5..R12. Also zeroes
// esum/counts/loss/total and 0xFF-inits pk (replaces memset nodes).
__global__ __launch_bounds__(256) void k_prep_embed(
    const float* __restrict__ embed, float* __restrict__ se,
    unsigned short* __restrict__ Bh, unsigned short* __restrict__ Bm,
    float* __restrict__ esum, float* __restrict__ counts,
    float* __restrict__ loss_ws, float* __restrict__ total_ws,
    unsigned long long* __restrict__ pk)
{
    __shared__ float tile[64][65];
    const int tid = threadIdx.x;
    const int t = blockIdx.x * 256 + tid;           // 0..32767
    const int j0 = blockIdx.x * 64;                 // 64 codes per block
    const int a = tid >> 6, b = tid & 63;

    // ws init (graph-node elimination)
    {
        float4 z = {0.f, 0.f, 0.f, 0.f};
        float4* e4 = (float4*)(esum + (size_t)t * 16);
        e4[0] = z; e4[1] = z; e4[2] = z; e4[3] = z;
        pk[t] = 0xFFFFFFFFFFFFFFFFull;
        if (t < NCODE) counts[t] = 0.f;
        if (t == 0) { *loss_ws = 0.f; *total_ws = 0.f; }
    }

#pragma unroll 4
    for (int p = 0; p < 16; ++p) {                  // coalesced embed load
        const int kk = p * 4 + a;
        tile[kk][b] = embed[(size_t)kk * NCODE + j0 + b];
    }
    __syncthreads();
#pragma unroll
    for (int i = 0; i < 16; ++i) {                  // -2-scaled splits (exact)
        const int k = a * 16 + i;
        float v = tile[k][b];
        float h = bfbits2f(f2bfbits(v));
        float r1 = v - h;
        float m = bfbits2f(f2bfbits(r1));
        Bh[(size_t)(j0 + b) * 64 + k] = f2bfbits(-2.f * h);   // exact scale
        Bm[(size_t)(j0 + b) * 64 + k] = f2bfbits(-2.f * m);
    }
    if (tid < 64) {                                 // exact sequential chain
        float s = 0.f;
#pragma unroll
        for (int k = 0; k < 64; ++k) { float v = tile[k][tid]; s = fmaf(v, v, s); }
        se[j0 + tid] = s;
    }
}

// ---------------- K1: MFMA GEMM-argmin (R11 shape + global_load_lds) ------
// Grid 2048: rb = blk>>3 (128 rows), split = blk&7 (1024 codes). 4 waves,
// wave owns 2 m-tiles. B staged via global_load_lds with XOR-swizzled slots
// (physical slot = logical ^ (code&7)); pitch 64 => 2-way banks (free).
// Math chains bit-identical to R11 (folded -2*B, acc init = sx+se).
__global__ __launch_bounds__(256) void k_argmin_mfma(
    const float* __restrict__ x, const float* __restrict__ pos,
    const unsigned short* __restrict__ Bh, const unsigned short* __restrict__ Bm,
    const float* __restrict__ se, unsigned long long* __restrict__ pk)
{
    __shared__ __align__(16) short lB[2][2][2048];   // [buf][h/m][32 codes x 64]
    const int tid = threadIdx.x;
    const int row0  = (blockIdx.x >> 3) * 128;
    const int split = blockIdx.x & 7;
    const int w = tid >> 6, lane = tid & 63;
    const int quad = lane >> 4, l15 = lane & 15;
    const int jbeg = split * CSPL;

    // ---- A-frags direct from global (identical split math to R7..R12) ----
    v8s af[2][2][2];
    float sqf[2];
#pragma unroll
    for (int mt = 0; mt < 2; ++mt) {
        const int n = row0 + w * 32 + mt * 16 + l15;
        const int c = (n >> 6) & 15, R = n & 63;
        const float* xrow = x + (size_t)n * 64;
        const float* prow = pos + ((R >> 2) * 16) * 256 + c * 16 + (R & 3) * 4;
        float sq = 0.f;
#pragma unroll
        for (int kh = 0; kh < 2; ++kh) {
            const int kb = kh * 32 + quad * 8;         // frag k-base
            const float4 x0 = *(const float4*)(xrow + kb);
            const float4 x1 = *(const float4*)(xrow + kb + 4);
            const float4 p0 = *(const float4*)(prow + (kb >> 2) * 256);
            const float4 p1 = *(const float4*)(prow + (kb >> 2) * 256 + 256);
            float vv[8] = {x0.x + p0.x, x0.y + p0.y, x0.z + p0.z, x0.w + p0.w,
                           x1.x + p1.x, x1.y + p1.y, x1.z + p1.z, x1.w + p1.w};
            v8s hf, mf;
#pragma unroll
            for (int i = 0; i < 8; ++i) {
                unsigned short uh = f2bfbits(vv[i]);
                float r1 = vv[i] - bfbits2f(uh);
                unsigned short um = f2bfbits(r1);
                hf[i] = (short)uh; mf[i] = (short)um;
                sq = fmaf(vv[i], vv[i], sq);
            }
            af[mt][0][kh] = hf; af[mt][1][kh] = mf;
        }
        sq += __shfl_xor(sq, 16, 64);                  // sum the 4 quads' k-parts
        sq += __shfl_xor(sq, 32, 64);                  // (row-const shift: argmin-inv)
        sqf[mt] = sq;
    }
    float sxr[2][4];
#pragma unroll
    for (int mt = 0; mt < 2; ++mt)
#pragma unroll
        for (int r = 0; r < 4; ++r)
            sxr[mt][r] = __shfl(sqf[mt], quad * 4 + r, 64);  // C-row = quad*4+reg

    // ---- staging: wave w stages codes w*8..w*8+7 of h and m, swizzled ----
    // global source slot s = (lane&7) ^ ((lane>>3)&7); dest = base + lane*16
    const int scode = lane >> 3;                       // 0..7 code-in-group
    const int sslot = (lane & 7) ^ (scode & 7);        // XOR-swizzled source slot
    float best[2][4]; int bidx[2][4];
#pragma unroll
    for (int mt = 0; mt < 2; ++mt)
#pragma unroll
        for (int r = 0; r < 4; ++r) { best[mt][r] = 3.402823466e38f; bidx[mt][r] = 0; }

    {   // prologue: chunk 0 -> buf 0
        const size_t g = (size_t)(jbeg + w * 8 + scode) * 64 + sslot * 8;
        gld_lds16(Bh + g, &lB[0][0][w * 512]);
        gld_lds16(Bm + g, &lB[0][1][w * 512]);
    }
    float cse0 = se[jbeg + l15], cse1 = se[jbeg + 16 + l15];
    __syncthreads();

    int buf = 0;
    for (int c = 0; c < CHUNKS; ++c) {
        float nse0 = 0.f, nse1 = 0.f;
        if (c < CHUNKS - 1) {                          // prefetch next -> buf^1
            const int n0n = jbeg + (c + 1) * 32;
            const size_t g = (size_t)(n0n + w * 8 + scode) * 64 + sslot * 8;
            gld_lds16(Bh + g, &lB[buf ^ 1][0][w * 512]);
            gld_lds16(Bm + g, &lB[buf ^ 1][1][w * 512]);
            nse0 = se[n0n + l15]; nse1 = se[n0n + 16 + l15];
        }
        const short* bbh = &lB[buf][0][0];
        const short* bbm = &lB[buf][1][0];
#pragma unroll
        for (int t16 = 0; t16 < 2; ++t16) {
            const int c16 = t16 * 16 + l15;
            const int sw = c16 & 7;
            const int base = c16 * 64;
            const v8s bh0 = *(const v8s*)&bbh[base + ((quad ^ sw) << 3)];
            const v8s bh1 = *(const v8s*)&bbh[base + (((quad + 4) ^ sw) << 3)];
            const v8s bm0 = *(const v8s*)&bbm[base + ((quad ^ sw) << 3)];
            const v8s bm1 = *(const v8s*)&bbm[base + (((quad + 4) ^ sw) << 3)];
            const float sev = t16 ? cse1 : cse0;
            const int j = jbeg + c * 32 + t16 * 16 + l15;
#pragma unroll
            for (int mt = 0; mt < 2; ++mt) {
                // acc init = sx + se; B carries -2 => d = acc directly
                v4f a = {sxr[mt][0] + sev, sxr[mt][1] + sev,
                         sxr[mt][2] + sev, sxr[mt][3] + sev};
                a = MFMA16(af[mt][1][0], bm0, a, 0, 0, 0);
                a = MFMA16(af[mt][1][1], bm1, a, 0, 0, 0);
                a = MFMA16(af[mt][1][0], bh0, a, 0, 0, 0);
                a = MFMA16(af[mt][1][1], bh1, a, 0, 0, 0);
                a = MFMA16(af[mt][0][0], bm0, a, 0, 0, 0);
                a = MFMA16(af[mt][0][1], bm1, a, 0, 0, 0);
                a = MFMA16(af[mt][0][0], bh0, a, 0, 0, 0);
                a = MFMA16(af[mt][0][1], bh1, a, 0, 0, 0);
#pragma unroll
                for (int r = 0; r < 4; ++r) {
                    if (a[r] < best[mt][r]) { best[mt][r] = a[r]; bidx[mt][r] = j; }
                }
            }
        }
        if (c < CHUNKS - 1) {
            cse0 = nse0; cse1 = nse1;
            __syncthreads();                           // drains vmcnt: buf^1 ready
            buf ^= 1;
        }
    }

    // lane-reduce over 16 lanes per row, then packed global atomicMin.
    // key = monotone(dist)<<32 | idx == (min dist, lower idx) tie-break.
#pragma unroll
    for (int mt = 0; mt < 2; ++mt)
#pragma unroll
    for (int r = 0; r < 4; ++r) {
        float bv = best[mt][r]; int bi = bidx[mt][r];
#pragma unroll
        for (int m = 8; m >= 1; m >>= 1) {
            float ov = __shfl_xor(bv, m, 64);
            int   oi = __shfl_xor(bi, m, 64);
            if (ov < bv || (ov == bv && oi < bi)) { bv = ov; bi = oi; }
        }
        if (l15 == 0) {
            const int row = row0 + w * 32 + mt * 16 + quad * 4 + r;
            unsigned int kb = __float_as_uint(bv);
            kb = kb ^ (((int)kb >> 31) | 0x80000000u);   // order-preserving uint
            unsigned long long key =
                ((unsigned long long)kb << 32) | (unsigned int)bi;
            atomicMin(&pk[row], key);
        }
    }
}

// ---------------- K2: quantize gather + loss + EMA scatter (float4) ------
// 2048 blocks x 256: 16 rows/block, 16 threads x float4 per row.
__global__ __launch_bounds__(256) void k_quant(
    const float* __restrict__ x, const float* __restrict__ pos,
    const unsigned short* __restrict__ Bh, const unsigned short* __restrict__ Bm,
    const unsigned long long* __restrict__ pk,
    float* __restrict__ embed_sum, float* __restrict__ counts,
    float* __restrict__ loss_ws, float* __restrict__ out_q,
    float* __restrict__ out_ind)
{
    const int tid = threadIdx.x;
    const int rr = tid >> 4, sl = tid & 15;      // row-in-block, 4-elem slot
    const int n = blockIdx.x * 16 + rr;
    const int k0 = sl * 4;
    int idx = (int)(unsigned int)(pk[n] & 0xFFFFFFFFull);   // same addr x16: bcast
    idx = idx < 0 ? 0 : (idx > NCODE - 1 ? NCODE - 1 : idx);
    if (sl == 0) out_ind[n] = (float)idx;

    const size_t eo = (size_t)idx * 64 + k0;
    const ushort4 uh = *(const ushort4*)(Bh + eo);
    const ushort4 um = *(const ushort4*)(Bm + eo);
    // e = -0.5*(-2h + -2m): exact power-of-2 scale => identical to h+m
    float qv[4] = {-0.5f * (bfbits2f(uh.x) + bfbits2f(um.x)),
                   -0.5f * (bfbits2f(uh.y) + bfbits2f(um.y)),
                   -0.5f * (bfbits2f(uh.z) + bfbits2f(um.z)),
                   -0.5f * (bfbits2f(uh.w) + bfbits2f(um.w))};
    const float4 xv = *(const float4*)(x + (size_t)n * 64 + k0);
    *(float4*)(out_q + (size_t)n * 64 + k0) = make_float4(qv[0], qv[1], qv[2], qv[3]);

    const int c = (n >> 6) & 15, R = n & 63;
    const float4 pv = *(const float4*)(pos + (((R >> 2) * 16 + sl) << 8)
                                           + (c << 4) + ((R & 3) << 2));
    atomicAdd(&embed_sum[eo + 0], xv.x + pv.x);
    atomicAdd(&embed_sum[eo + 1], xv.y + pv.y);
    atomicAdd(&embed_sum[eo + 2], xv.z + pv.z);
    atomicAdd(&embed_sum[eo + 3], xv.w + pv.w);
    if (sl == 0) atomicAdd(&counts[idx], 1.0f);

    float sq = (qv[0] - xv.x) * (qv[0] - xv.x) + (qv[1] - xv.y) * (qv[1] - xv.y)
             + (qv[2] - xv.z) * (qv[2] - xv.z) + (qv[3] - xv.w) * (qv[3] - xv.w);
#pragma unroll
    for (int m = 32; m >= 1; m >>= 1) sq += __shfl_xor(sq, m, 64);
    __shared__ float ls[4];
    if ((tid & 63) == 0) ls[tid >> 6] = sq;
    __syncthreads();
    if (tid == 0) atomicAdd(loss_ws, ls[0] + ls[1] + ls[2] + ls[3]);
}

// ---------------- K3: cluster/total/eavg/embed/loss (merged final) --------
__global__ __launch_bounds__(256) void k_final(
    const float* __restrict__ cluster, const float* __restrict__ counts,
    const float* __restrict__ embed_avg, const float* __restrict__ embed_sum,
    const float* __restrict__ loss_ws,
    float* __restrict__ out_loss, float* __restrict__ out_cluster,
    float* __restrict__ out_eavg, float* __restrict__ out_embed)
{
    __shared__ float tile[64][65];
    __shared__ float smv[64];
    __shared__ float ls[4];
    __shared__ float tot_s;
    const int tid = threadIdx.x;
    const int j0 = blockIdx.x * 64;
    const int a = tid >> 6, b = tid & 63;

    // total = sum(new_cluster), identical order every block
    float s = 0.f;
#pragma unroll 4
    for (int p = 0; p < 32; ++p) {
        const int j = p * 256 + tid;
        s += 0.8f * cluster[j] + 0.2f * counts[j];
    }
#pragma unroll
    for (int m = 32; m >= 1; m >>= 1) s += __shfl_xor(s, m, 64);
    if ((tid & 63) == 0) ls[tid >> 6] = s;

#pragma unroll 4
    for (int p = 0; p < 16; ++p) {               // load esum tile coalesced
        const int jj = p * 4 + a;
        tile[jj][b] = embed_sum[(size_t)(j0 + jj) * 64 + b];
    }
    __syncthreads();
    if (tid == 0) tot_s = ls[0] + ls[1] + ls[2] + ls[3];
    __syncthreads();
    if (tid < 64) {
        const float total = tot_s;
        float nc = 0.8f * cluster[j0 + tid] + 0.2f * counts[j0 + tid];
        out_cluster[j0 + tid] = nc;
        smv[tid] = (nc + 1e-5f) / (total + 0.08192f) * total;
    }
    __syncthreads();

#pragma unroll 4
    for (int p = 0; p < 16; ++p) {               // write transposed, coalesced
        const int kk = p * 4 + a;
        const size_t e = (size_t)kk * NCODE + j0 + b;
        float ea = 0.8f * embed_avg[e] + 0.2f * tile[b][kk];
        out_eavg[e]  = ea;
        out_embed[e] = ea / smv[b];
    }
    if (blockIdx.x == 0 && tid == 0)
        *out_loss = *loss_ws * (1.0f / 2097152.0f);
}

extern "C" void kernel_launch(void* const* d_in, const int* in_sizes, int n_in,
                              void* d_out, int out_size, void* d_ws, size_t ws_size,
                              hipStream_t stream) {
    (void)in_sizes; (void)n_in; (void)out_size; (void)ws_size;
    const float* x        = (const float*)d_in[0];   // (32,16,64,64)
    const float* embed    = (const float*)d_in[1];   // (64,8192)
    const float* pos      = (const float*)d_in[2];   // (2048,256)
    const float* cluster  = (const float*)d_in[3];   // (8192,)
    const float* eavg     = (const float*)d_in[4];   // (64,8192)
    float* out = (float*)d_out;                      // fp32 outputs, concatenated

    char* ws = (char*)d_ws;
    float* w_loss   = (float*)(ws + WS_LOSS);
    float* w_total  = (float*)(ws + WS_TOTAL);
    float* w_se     = (float*)(ws + WS_SE);
    float* w_counts = (float*)(ws + WS_COUNTS);
    float* w_esum   = (float*)(ws + WS_ESUM);
    unsigned long long* w_pk = (unsigned long long*)(ws + WS_PK);
    unsigned short* w_bh = (unsigned short*)(ws + WS_BH);
    unsigned short* w_bm = (unsigned short*)(ws + WS_BM);

    // 4 graph nodes; prep performs all workspace init (no memsets)
    k_prep_embed<<<NROWS / 256, 256, 0, stream>>>(embed, w_se, w_bh, w_bm,
                                                  w_esum, w_counts, w_loss,
                                                  w_total, w_pk);
    k_argmin_mfma<<<(NROWS / 128) * NSPL, 256, 0, stream>>>(
        x, pos, w_bh, w_bm, w_se, w_pk);
    k_quant<<<NROWS / 16, 256, 0, stream>>>(x, pos, w_bh, w_bm, w_pk,
                                            w_esum, w_counts, w_loss,
                                            out + OUT_Q, out + OUT_IND);
    k_final<<<NCODE / 64, 256, 0, stream>>>(cluster, w_counts, eavg, w_esum,
                                            w_loss, out + OUT_LOSS,
                                            out + OUT_CLUSTER,
                                            out + OUT_EAVG, out + OUT_EMBED);
}

// Round 14
// 243.300 us; speedup vs baseline: 1.0229x; 1.0072x over previous
//
#include <hip/hip_runtime.h>
#include <hip/hip_bf16.h>

#define NROWS   32768          // 32*16*64 rows of dim 64
#define NCODE   8192
#define NSPL    8              // code-dimension splits
#define CSPL    (NCODE / NSPL) // 1024 codes per block
#define CHUNKS  (CSPL / 32)    // 32 LDS chunks of 32 codes

// d_out element offsets (FLOAT32 elements):
// quantize(2097152), ind(32768), loss(1), cluster(8192), eavg(524288), embed(524288)
#define OUT_Q        0
#define OUT_IND      2097152
#define OUT_LOSS     2129920
#define OUT_CLUSTER  2129921
#define OUT_EAVG     2138113
#define OUT_EMBED    2662401

// workspace byte offsets — total 4,522,048 bytes
#define WS_LOSS     0            // f32 [1]
#define WS_TOTAL    4            // f32 [1]
#define WS_SE       64           // f32 [8192]  ||e_j||^2
#define WS_COUNTS   32832        // f32 [8192]
#define WS_ESUM     65600        // f32 [8192][64] ([code][k])
#define WS_PK       2162752      // u64 [32768] packed (dist|idx)
#define WS_BH       2424896      // bf16 bits [8192][64] = -2 * high split
#define WS_BM       3473472      // bf16 bits [8192][64] = -2 * mid split
// end: 4,522,048

typedef short v8s __attribute__((ext_vector_type(8)));
typedef float v4f __attribute__((ext_vector_type(4)));
#define MFMA16 __builtin_amdgcn_mfma_f32_16x16x32_bf16

__device__ __forceinline__ int pos_off(int c, int R, int k) {
    // pos_emb[(R>>2)*16 + (k>>2)][c*16 + (R&3)*4 + (k&3)], row stride 256
    return (((R >> 2) * 16 + (k >> 2)) << 8) + (c << 4) + ((R & 3) << 2) + (k & 3);
}

__device__ __forceinline__ unsigned short f2bfbits(float v) {
    __hip_bfloat16 h = __float2bfloat16(v);           // RNE
    union { __hip_bfloat16 h; unsigned short u; } c; c.h = h; return c.u;
}
__device__ __forceinline__ float bfbits2f(unsigned short u) {
    union { unsigned short u; __hip_bfloat16 h; } c; c.u = u; return __bfloat162float(c.h);
}

// direct global->LDS 16B DMA (gfx950): dest = wave-uniform base + lane*16
__device__ __forceinline__ void gld_lds16(const unsigned short* g, short* lds_base) {
    __builtin_amdgcn_global_load_lds(
        (const __attribute__((address_space(1))) unsigned int*)g,
        (__attribute__((address_space(3))) unsigned int*)lds_base, 16, 0, 0);
}

// ---------------- K0: B' = -2*splits, ||e||^2, and all ws init ------------
// 128 blocks x 256. se chain bit-identical to R5..R13. Split writes are now
// COALESCED: lane index = k, so each wave-store covers one code row's 128 B
// contiguously (R13 layout had lane = code -> 64 txns/inst, ~1M scattered
// 2B RMW writes). LDS column read tile[b][c2] is stride-65 -> conflict-free.
__global__ __launch_bounds__(256) void k_prep_embed(
    const float* __restrict__ embed, float* __restrict__ se,
    unsigned short* __restrict__ Bh, unsigned short* __restrict__ Bm,
    float* __restrict__ esum, float* __restrict__ counts,
    float* __restrict__ loss_ws, float* __restrict__ total_ws,
    unsigned long long* __restrict__ pk)
{
    __shared__ float tile[64][65];
    const int tid = threadIdx.x;
    const int t = blockIdx.x * 256 + tid;           // 0..32767
    const int j0 = blockIdx.x * 64;                 // 64 codes per block
    const int a = tid >> 6, b = tid & 63;

    // ws init (graph-node elimination)
    {
        float4 z = {0.f, 0.f, 0.f, 0.f};
        float4* e4 = (float4*)(esum + (size_t)t * 16);
        e4[0] = z; e4[1] = z; e4[2] = z; e4[3] = z;
        pk[t] = 0xFFFFFFFFFFFFFFFFull;
        if (t < NCODE) counts[t] = 0.f;
        if (t == 0) { *loss_ws = 0.f; *total_ws = 0.f; }
    }

#pragma unroll 4
    for (int p = 0; p < 16; ++p) {                  // coalesced embed load
        const int kk = p * 4 + a;
        tile[kk][b] = embed[(size_t)kk * NCODE + j0 + b];
    }
    __syncthreads();
#pragma unroll
    for (int i = 0; i < 16; ++i) {                  // -2-scaled splits (exact)
        const int c2 = a * 16 + i;                  // code-in-tile; k = b (lane)
        float v = tile[b][c2];                      // column read: 2-way, free
        float h = bfbits2f(f2bfbits(v));
        float r1 = v - h;
        float m = bfbits2f(f2bfbits(r1));
        Bh[(size_t)(j0 + c2) * 64 + b] = f2bfbits(-2.f * h);  // 128B/wave, 1 txn
        Bm[(size_t)(j0 + c2) * 64 + b] = f2bfbits(-2.f * m);
    }
    if (tid < 64) {                                 // exact sequential chain
        float s = 0.f;
#pragma unroll
        for (int k = 0; k < 64; ++k) { float v = tile[k][tid]; s = fmaf(v, v, s); }
        se[j0 + tid] = s;
    }
}

// ---------------- K1: MFMA GEMM-argmin (R13, frozen at plateau) -----------
// Grid 2048: rb = blk>>3 (128 rows), split = blk&7 (1024 codes). 4 waves,
// wave owns 2 m-tiles. B staged via global_load_lds with XOR-swizzled slots
// (physical slot = logical ^ (code&7)); pitch 64 => 2-way banks (free).
// Math chains bit-identical to R11 (folded -2*B, acc init = sx+se).
__global__ __launch_bounds__(256) void k_argmin_mfma(
    const float* __restrict__ x, const float* __restrict__ pos,
    const unsigned short* __restrict__ Bh, const unsigned short* __restrict__ Bm,
    const float* __restrict__ se, unsigned long long* __restrict__ pk)
{
    __shared__ __align__(16) short lB[2][2][2048];   // [buf][h/m][32 codes x 64]
    const int tid = threadIdx.x;
    const int row0  = (blockIdx.x >> 3) * 128;
    const int split = blockIdx.x & 7;
    const int w = tid >> 6, lane = tid & 63;
    const int quad = lane >> 4, l15 = lane & 15;
    const int jbeg = split * CSPL;

    // ---- A-frags direct from global (identical split math to R7..R13) ----
    v8s af[2][2][2];
    float sqf[2];
#pragma unroll
    for (int mt = 0; mt < 2; ++mt) {
        const int n = row0 + w * 32 + mt * 16 + l15;
        const int c = (n >> 6) & 15, R = n & 63;
        const float* xrow = x + (size_t)n * 64;
        const float* prow = pos + ((R >> 2) * 16) * 256 + c * 16 + (R & 3) * 4;
        float sq = 0.f;
#pragma unroll
        for (int kh = 0; kh < 2; ++kh) {
            const int kb = kh * 32 + quad * 8;         // frag k-base
            const float4 x0 = *(const float4*)(xrow + kb);
            const float4 x1 = *(const float4*)(xrow + kb + 4);
            const float4 p0 = *(const float4*)(prow + (kb >> 2) * 256);
            const float4 p1 = *(const float4*)(prow + (kb >> 2) * 256 + 256);
            float vv[8] = {x0.x + p0.x, x0.y + p0.y, x0.z + p0.z, x0.w + p0.w,
                           x1.x + p1.x, x1.y + p1.y, x1.z + p1.z, x1.w + p1.w};
            v8s hf, mf;
#pragma unroll
            for (int i = 0; i < 8; ++i) {
                unsigned short uh = f2bfbits(vv[i]);
                float r1 = vv[i] - bfbits2f(uh);
                unsigned short um = f2bfbits(r1);
                hf[i] = (short)uh; mf[i] = (short)um;
                sq = fmaf(vv[i], vv[i], sq);
            }
            af[mt][0][kh] = hf; af[mt][1][kh] = mf;
        }
        sq += __shfl_xor(sq, 16, 64);                  // sum the 4 quads' k-parts
        sq += __shfl_xor(sq, 32, 64);                  // (row-const shift: argmin-inv)
        sqf[mt] = sq;
    }
    float sxr[2][4];
#pragma unroll
    for (int mt = 0; mt < 2; ++mt)
#pragma unroll
        for (int r = 0; r < 4; ++r)
            sxr[mt][r] = __shfl(sqf[mt], quad * 4 + r, 64);  // C-row = quad*4+reg

    // ---- staging: wave w stages codes w*8..w*8+7 of h and m, swizzled ----
    const int scode = lane >> 3;                       // 0..7 code-in-group
    const int sslot = (lane & 7) ^ (scode & 7);        // XOR-swizzled source slot
    float best[2][4]; int bidx[2][4];
#pragma unroll
    for (int mt = 0; mt < 2; ++mt)
#pragma unroll
        for (int r = 0; r < 4; ++r) { best[mt][r] = 3.402823466e38f; bidx[mt][r] = 0; }

    {   // prologue: chunk 0 -> buf 0
        const size_t g = (size_t)(jbeg + w * 8 + scode) * 64 + sslot * 8;
        gld_lds16(Bh + g, &lB[0][0][w * 512]);
        gld_lds16(Bm + g, &lB[0][1][w * 512]);
    }
    float cse0 = se[jbeg + l15], cse1 = se[jbeg + 16 + l15];
    __syncthreads();

    int buf = 0;
    for (int c = 0; c < CHUNKS; ++c) {
        float nse0 = 0.f, nse1 = 0.f;
        if (c < CHUNKS - 1) {                          // prefetch next -> buf^1
            const int n0n = jbeg + (c + 1) * 32;
            const size_t g = (size_t)(n0n + w * 8 + scode) * 64 + sslot * 8;
            gld_lds16(Bh + g, &lB[buf ^ 1][0][w * 512]);
            gld_lds16(Bm + g, &lB[buf ^ 1][1][w * 512]);
            nse0 = se[n0n + l15]; nse1 = se[n0n + 16 + l15];
        }
        const short* bbh = &lB[buf][0][0];
        const short* bbm = &lB[buf][1][0];
#pragma unroll
        for (int t16 = 0; t16 < 2; ++t16) {
            const int c16 = t16 * 16 + l15;
            const int sw = c16 & 7;
            const int base = c16 * 64;
            const v8s bh0 = *(const v8s*)&bbh[base + ((quad ^ sw) << 3)];
            const v8s bh1 = *(const v8s*)&bbh[base + (((quad + 4) ^ sw) << 3)];
            const v8s bm0 = *(const v8s*)&bbm[base + ((quad ^ sw) << 3)];
            const v8s bm1 = *(const v8s*)&bbm[base + (((quad + 4) ^ sw) << 3)];
            const float sev = t16 ? cse1 : cse0;
            const int j = jbeg + c * 32 + t16 * 16 + l15;
#pragma unroll
            for (int mt = 0; mt < 2; ++mt) {
                // acc init = sx + se; B carries -2 => d = acc directly
                v4f a = {sxr[mt][0] + sev, sxr[mt][1] + sev,
                         sxr[mt][2] + sev, sxr[mt][3] + sev};
                a = MFMA16(af[mt][1][0], bm0, a, 0, 0, 0);
                a = MFMA16(af[mt][1][1], bm1, a, 0, 0, 0);
                a = MFMA16(af[mt][1][0], bh0, a, 0, 0, 0);
                a = MFMA16(af[mt][1][1], bh1, a, 0, 0, 0);
                a = MFMA16(af[mt][0][0], bm0, a, 0, 0, 0);
                a = MFMA16(af[mt][0][1], bm1, a, 0, 0, 0);
                a = MFMA16(af[mt][0][0], bh0, a, 0, 0, 0);
                a = MFMA16(af[mt][0][1], bh1, a, 0, 0, 0);
#pragma unroll
                for (int r = 0; r < 4; ++r) {
                    if (a[r] < best[mt][r]) { best[mt][r] = a[r]; bidx[mt][r] = j; }
                }
            }
        }
        if (c < CHUNKS - 1) {
            cse0 = nse0; cse1 = nse1;
            __syncthreads();                           // drains vmcnt: buf^1 ready
            buf ^= 1;
        }
    }

    // lane-reduce over 16 lanes per row, then packed global atomicMin.
    // key = monotone(dist)<<32 | idx == (min dist, lower idx) tie-break.
#pragma unroll
    for (int mt = 0; mt < 2; ++mt)
#pragma unroll
    for (int r = 0; r < 4; ++r) {
        float bv = best[mt][r]; int bi = bidx[mt][r];
#pragma unroll
        for (int m = 8; m >= 1; m >>= 1) {
            float ov = __shfl_xor(bv, m, 64);
            int   oi = __shfl_xor(bi, m, 64);
            if (ov < bv || (ov == bv && oi < bi)) { bv = ov; bi = oi; }
        }
        if (l15 == 0) {
            const int row = row0 + w * 32 + mt * 16 + quad * 4 + r;
            unsigned int kb = __float_as_uint(bv);
            kb = kb ^ (((int)kb >> 31) | 0x80000000u);   // order-preserving uint
            unsigned long long key =
                ((unsigned long long)kb << 32) | (unsigned int)bi;
            atomicMin(&pk[row], key);
        }
    }
}

// ---------------- K2: quantize gather + loss + EMA scatter (float4) ------
// 2048 blocks x 256: 16 rows/block, 16 threads x float4 per row.
__global__ __launch_bounds__(256) void k_quant(
    const float* __restrict__ x, const float* __restrict__ pos,
    const unsigned short* __restrict__ Bh, const unsigned short* __restrict__ Bm,
    const unsigned long long* __restrict__ pk,
    float* __restrict__ embed_sum, float* __restrict__ counts,
    float* __restrict__ loss_ws, float* __restrict__ out_q,
    float* __restrict__ out_ind)
{
    const int tid = threadIdx.x;
    const int rr = tid >> 4, sl = tid & 15;      // row-in-block, 4-elem slot
    const int n = blockIdx.x * 16 + rr;
    const int k0 = sl * 4;
    int idx = (int)(unsigned int)(pk[n] & 0xFFFFFFFFull);   // same addr x16: bcast
    idx = idx < 0 ? 0 : (idx > NCODE - 1 ? NCODE - 1 : idx);
    if (sl == 0) out_ind[n] = (float)idx;

    const size_t eo = (size_t)idx * 64 + k0;
    const ushort4 uh = *(const ushort4*)(Bh + eo);
    const ushort4 um = *(const ushort4*)(Bm + eo);
    // e = -0.5*(-2h + -2m): exact power-of-2 scale => identical to h+m
    float qv[4] = {-0.5f * (bfbits2f(uh.x) + bfbits2f(um.x)),
                   -0.5f * (bfbits2f(uh.y) + bfbits2f(um.y)),
                   -0.5f * (bfbits2f(uh.z) + bfbits2f(um.z)),
                   -0.5f * (bfbits2f(uh.w) + bfbits2f(um.w))};
    const float4 xv = *(const float4*)(x + (size_t)n * 64 + k0);
    *(float4*)(out_q + (size_t)n * 64 + k0) = make_float4(qv[0], qv[1], qv[2], qv[3]);

    const int c = (n >> 6) & 15, R = n & 63;
    const float4 pv = *(const float4*)(pos + (((R >> 2) * 16 + sl) << 8)
                                           + (c << 4) + ((R & 3) << 2));
    atomicAdd(&embed_sum[eo + 0], xv.x + pv.x);
    atomicAdd(&embed_sum[eo + 1], xv.y + pv.y);
    atomicAdd(&embed_sum[eo + 2], xv.z + pv.z);
    atomicAdd(&embed_sum[eo + 3], xv.w + pv.w);
    if (sl == 0) atomicAdd(&counts[idx], 1.0f);

    float sq = (qv[0] - xv.x) * (qv[0] - xv.x) + (qv[1] - xv.y) * (qv[1] - xv.y)
             + (qv[2] - xv.z) * (qv[2] - xv.z) + (qv[3] - xv.w) * (qv[3] - xv.w);
#pragma unroll
    for (int m = 32; m >= 1; m >>= 1) sq += __shfl_xor(sq, m, 64);
    __shared__ float ls[4];
    if ((tid & 63) == 0) ls[tid >> 6] = sq;
    __syncthreads();
    if (tid == 0) atomicAdd(loss_ws, ls[0] + ls[1] + ls[2] + ls[3]);
}

// ---------------- K3: cluster/total/eavg/embed/loss (merged final) --------
__global__ __launch_bounds__(256) void k_final(
    const float* __restrict__ cluster, const float* __restrict__ counts,
    const float* __restrict__ embed_avg, const float* __restrict__ embed_sum,
    const float* __restrict__ loss_ws,
    float* __restrict__ out_loss, float* __restrict__ out_cluster,
    float* __restrict__ out_eavg, float* __restrict__ out_embed)
{
    __shared__ float tile[64][65];
    __shared__ float smv[64];
    __shared__ float ls[4];
    __shared__ float tot_s;
    const int tid = threadIdx.x;
    const int j0 = blockIdx.x * 64;
    const int a = tid >> 6, b = tid & 63;

    // total = sum(new_cluster), identical order every block
    float s = 0.f;
#pragma unroll 4
    for (int p = 0; p < 32; ++p) {
        const int j = p * 256 + tid;
        s += 0.8f * cluster[j] + 0.2f * counts[j];
    }
#pragma unroll
    for (int m = 32; m >= 1; m >>= 1) s += __shfl_xor(s, m, 64);
    if ((tid & 63) == 0) ls[tid >> 6] = s;

#pragma unroll 4
    for (int p = 0; p < 16; ++p) {               // load esum tile coalesced
        const int jj = p * 4 + a;
        tile[jj][b] = embed_sum[(size_t)(j0 + jj) * 64 + b];
    }
    __syncthreads();
    if (tid == 0) tot_s = ls[0] + ls[1] + ls[2] + ls[3];
    __syncthreads();
    if (tid < 64) {
        const float total = tot_s;
        float nc = 0.8f * cluster[j0 + tid] + 0.2f * counts[j0 + tid];
        out_cluster[j0 + tid] = nc;
        smv[tid] = (nc + 1e-5f) / (total + 0.08192f) * total;
    }
    __syncthreads();

#pragma unroll 4
    for (int p = 0; p < 16; ++p) {               // write transposed, coalesced
        const int kk = p * 4 + a;
        const size_t e = (size_t)kk * NCODE + j0 + b;
        float ea = 0.8f * embed_avg[e] + 0.2f * tile[b][kk];
        out_eavg[e]  = ea;
        out_embed[e] = ea / smv[b];
    }
    if (blockIdx.x == 0 && tid == 0)
        *out_loss = *loss_ws * (1.0f / 2097152.0f);
}

extern "C" void kernel_launch(void* const* d_in, const int* in_sizes, int n_in,
                              void* d_out, int out_size, void* d_ws, size_t ws_size,
                              hipStream_t stream) {
    (void)in_sizes; (void)n_in; (void)out_size; (void)ws_size;
    const float* x        = (const float*)d_in[0];   // (32,16,64,64)
    const float* embed    = (const float*)d_in[1];   // (64,8192)
    const float* pos      = (const float*)d_in[2];   // (2048,256)
    const float* cluster  = (const float*)d_in[3];   // (8192,)
    const float* eavg     = (const float*)d_in[4];   // (64,8192)
    float* out = (float*)d_out;                      // fp32 outputs, concatenated

    char* ws = (char*)d_ws;
    float* w_loss   = (float*)(ws + WS_LOSS);
    float* w_total  = (float*)(ws + WS_TOTAL);
    float* w_se     = (float*)(ws + WS_SE);
    float* w_counts = (float*)(ws + WS_COUNTS);
    float* w_esum   = (float*)(ws + WS_ESUM);
    unsigned long long* w_pk = (unsigned long long*)(ws + WS_PK);
    unsigned short* w_bh = (unsigned short*)(ws + WS_BH);
    unsigned short* w_bm = (unsigned short*)(ws + WS_BM);

    // 4 graph nodes; prep performs all workspace init (no memsets)
    k_prep_embed<<<NROWS / 256, 256, 0, stream>>>(embed, w_se, w_bh, w_bm,
                                                  w_esum, w_counts, w_loss,
                                                  w_total, w_pk);
    k_argmin_mfma<<<(NROWS / 128) * NSPL, 256, 0, stream>>>(
        x, pos, w_bh, w_bm, w_se, w_pk);
    k_quant<<<NROWS / 16, 256, 0, stream>>>(x, pos, w_bh, w_bm, w_pk,
                                            w_esum, w_counts, w_loss,
                                            out + OUT_Q, out + OUT_IND);
    k_final<<<NCODE / 64, 256, 0, stream>>>(cluster, w_counts, eavg, w_esum,
                                            w_loss, out + OUT_LOSS,
                                            out + OUT_CLUSTER,
                                            out + OUT_EAVG, out + OUT_EMBED);
}